// Round 16
// baseline (107.218 us; speedup 1.0000x reference)
//
#include <hip/hip_runtime.h>
#include <hip/hip_fp16.h>

// B=32768, D=128, L=3, R=64, O=64. fp32 in/out, f16 MFMA compute.
// TB=64, 512 WGs x 512 threads (8 waves: p/kh/sb), TWO WGs per CU (LDS
// 74752B) -> two independent barrier domains self-stagger, overlapping
// LDS/DMA/MFMA across WGs. Per-iteration mechanics from r11: gathered
// conflict-free ct layout [d][sb][kh][kbL][lane][16B] (lane-contiguous
// ds_read_b128, read-once per fragment), drain-0 2-slot 16KB ring, staged
// non-atomic reduce, T buffer, xn reads hoisted above the barrier.
// FIX vs r15: main loop runs 64 iterations (16KB chunk = 2 d's; 64x2 = 128
// d's) — r15 ran 32 and contracted only half of K (same bug as r13).
typedef _Float16 f16x8 __attribute__((ext_vector_type(8)));
typedef float f32x16 __attribute__((ext_vector_type(16)));

union H2x4 { f16x8 v; __half2 h2[4]; unsigned u[4]; };
union U1H2 { unsigned u; __half2 h; };

#define TB 64               // batch rows per workgroup (512 WGs = 2/CU)
// LDS layout (bytes)
#define SLOT0_OFF 0         // ring slot0 (16KB) = xn0 in phase0/stageA; scr0
#define SLOT1_OFF 16384     // ring slot1 (16KB); scr1
#define T_OFF     32768     // T buffer [64][64]f16, 128B rows, XOR swz = 8KB
#define XN12_OFF  40960     // xn slices 1,2: [d<128] pitch 264B = 33792B
#define SMEM_BYTES 74752    // 2 WGs/CU: 149504 <= 163840 (r3-proven footprint)
// workspace layout (bytes)
#define WS_CT1   0          // core1 -> [d][sb][kh][kbL][lane][16B] f16, 1MB
#define WS_CT2   1048576    // core2 same
#define WS_L0T   2097152    // layer0^T [r][d] f16, 16KB
#define WS_LASTT 2113536    // last^T [o][r] f16, 8KB

#define WAITBAR0() asm volatile("s_waitcnt vmcnt(0)\n\ts_barrier" ::: "memory")

__device__ __forceinline__ void gload_lds16(const void* g, void* l) {
  __builtin_amdgcn_global_load_lds(
      (const __attribute__((address_space(1))) unsigned int*)g,
      (__attribute__((address_space(3))) unsigned int*)l, 16, 0, 0);
}

// stage one 16KB core chunk (2 d's): 2 loads/thread at 512 threads
__device__ __forceinline__ void issue_chunk16(const unsigned char* g,
                                              unsigned char* l, int tid) {
  gload_lds16(g + tid * 16, l + tid * 16);
  gload_lds16(g + tid * 16 + 8192, l + tid * 16 + 8192);
}

__device__ __forceinline__ unsigned pack_h2(float a, float b) {
  return (unsigned)__half_as_ushort(__float2half(a)) |
         ((unsigned)__half_as_ushort(__float2half(b)) << 16);
}

// 4-way (p x kh) cross-wave reduce, staged non-atomic (r3/r8 scheme):
// scr(kh) = 16KB f32 [64][64] in ring slot kh (both dead at reduce time),
// p0 writes, p1 adds, p0 combines kh-pair -> T [64][64] f16 swizzled.
__device__ __forceinline__ void reduce_T(unsigned char* smem, f32x16 a0, f32x16 a1,
                                         int p, int kh, int h, int scol) {
  float* scr = (float*)(smem + (kh ? SLOT1_OFF : SLOT0_OFF));
  __syncthreads();
  if (p == 0) {
#pragma unroll
    for (int j = 0; j < 16; ++j) {
      const int r0 = (j & 3) + 8 * (j >> 2) + 4 * h;
      scr[r0 * 64 + scol] = a0[j];
      scr[(32 + r0) * 64 + scol] = a1[j];
    }
  }
  __syncthreads();
  if (p == 1) {
#pragma unroll
    for (int j = 0; j < 16; ++j) {
      const int r0 = (j & 3) + 8 * (j >> 2) + 4 * h;
      scr[r0 * 64 + scol] += a0[j];
      scr[(32 + r0) * 64 + scol] += a1[j];
    }
  }
  __syncthreads();
  if (p == 0) {  // wave (kh,sb) combines rows kh*32.. across the kh-pair
    const float* s0 = (const float*)(smem + SLOT0_OFF);
    const float* s1 = (const float*)(smem + SLOT1_OFF);
#pragma unroll
    for (int j = 0; j < 16; ++j) {
      const int r0 = (j & 3) + 8 * (j >> 2) + 4 * h;
      const int row = kh * 32 + r0;
      const float vsum = s0[row * 64 + scol] + s1[row * 64 + scol];
      *(__half*)(smem + T_OFF + row * 128 + ((2 * scol) ^ ((row & 7) << 4))) =
          __float2half(vsum);
    }
  }
  __syncthreads();
}

// ---- prep: cast weights to f16 in the layouts the main kernel wants ----
__global__ void __launch_bounds__(512) tt_prep(
    const float* __restrict__ layer0, const float* __restrict__ core1,
    const float* __restrict__ core2, const float* __restrict__ last,
    unsigned char* __restrict__ ws) {
  const int tid = blockIdx.x * 512 + threadIdx.x;
  if (tid < 524288) {                       // ct: 2 x 262144 words
    const int which = tid >> 18;
    const int w = tid & 262143;
    const float* core = which ? core2 : core1;
    unsigned char* ct = ws + (which ? WS_CT2 : WS_CT1);
    // dest layout: [d][sb][kh][kbL][lp=l31*2+h][16B]; offset == w*4 (linear)
    const int j   = w & 3;                  // word within 16B chunk
    const int lp  = (w >> 2) & 63;          // l31*2 + h
    const int blk = w >> 8;                 // d*8 + sb*4 + kh*2 + kbL
    const int kbL = blk & 1;
    const int kh  = (blk >> 1) & 1;
    const int sb  = (blk >> 2) & 1;
    const int d   = blk >> 3;
    const int hh  = lp & 1;
    const int l31 = lp >> 1;
    const int s   = sb * 32 + l31;
    const int r0  = kh * 32 + kbL * 16 + hh * 8 + 2 * j;
    const unsigned val = pack_h2(core[r0 * 8192 + d * 64 + s],
                                 core[(r0 + 1) * 8192 + d * 64 + s]);
    *(unsigned*)(ct + (size_t)w * 4) = val;
  } else if (tid < 528384) {                // l0t: 4096 words, [r][d] f16 (256B rows)
    const int w = tid - 524288;
    const int r = w >> 6, j = w & 63, d = 2 * j;
    const unsigned val = pack_h2(layer0[d * 64 + r], layer0[(d + 1) * 64 + r]);
    *(unsigned*)(ws + WS_L0T + r * 256 + 4 * j) = val;
  } else if (tid < 530432) {                // lastT: 2048 words, [o][r] f16 (128B rows)
    const int w = tid - 528384;
    const int o = w >> 5, j = w & 31, r = 2 * j;
    const unsigned val = pack_h2(last[r * 64 + o], last[(r + 1) * 64 + o]);
    *(unsigned*)(ws + WS_LASTT + o * 128 + 4 * j) = val;
  }
}

// ---- fused main kernel: LN + 4-stage tensor-train chain ----
__global__ void __launch_bounds__(512, 4) tt_fused(
    const float* __restrict__ x, const float* __restrict__ lnw,
    const float* __restrict__ lnb, const unsigned char* __restrict__ ws,
    float* __restrict__ out) {
  __shared__ alignas(16) unsigned char smem[SMEM_BYTES];
  const int tid = threadIdx.x;
  const int wid = tid >> 6;
  const int lane = tid & 63;
  const int l31 = lane & 31;
  const int h = lane >> 5;
  const int p  = wid & 1;           // d-parity within chunk
  const int kh = (wid >> 1) & 1;    // r-half (K-split over r)
  const int sb = (wid >> 2) & 1;    // s-block (32 cols)
  const int bg0 = blockIdx.x * TB;
  const int scol = sb * 32 + l31;   // this lane's B-col
  const int lp16 = (l31 * 2 + h) * 16;
  const int swzA = (l31 & 7) << 4;  // == (row&7)<<4 for rows mb*32+l31

  // ---------- phase 0: LN; xn0 -> slot0 [row][256B swz]; xn1,2 -> XN12 ----------
  {
    float wv[6], bv[6];
#pragma unroll
    for (int k = 0; k < 6; ++k) { wv[k] = lnw[lane + 64 * k]; bv[k] = lnb[lane + 64 * k]; }
#pragma unroll
    for (int rr = 0; rr < 8; ++rr) {
      const int row = wid * 8 + rr;           // 8 waves x 8 = 64 rows
      const float* xrow = x + (size_t)(bg0 + row) * 384;
      float v[6];
#pragma unroll
      for (int k = 0; k < 6; ++k) v[k] = xrow[lane + 64 * k];
      float s = 0.f, ss = 0.f;
#pragma unroll
      for (int k = 0; k < 6; ++k) { s += v[k]; ss += v[k] * v[k]; }
#pragma unroll
      for (int m = 1; m < 64; m <<= 1) { s += __shfl_xor(s, m); ss += __shfl_xor(ss, m); }
      const float mu = s * (1.f / 384.f);
      const float var = ss * (1.f / 384.f) - mu * mu;
      const float rstd = rsqrtf(var + 1e-5f);
#pragma unroll
      for (int k = 0; k < 6; ++k) {
        const int i = lane + 64 * k;          // i = 3*d + sl
        const int d = i / 3;
        const int sl = i - 3 * d;
        const float xv = (v[k] - mu) * rstd * wv[k] + bv[k];
        if (sl == 0) {
          *(__half*)(smem + SLOT0_OFF + row * 256 + ((2 * d) ^ ((row & 7) << 4))) =
              __float2half(xv);
        } else {
          *(__half*)(smem + XN12_OFF + d * 264 + 4 * row + 2 * (sl - 1)) =
              __float2half(xv);
        }
      }
    }
  }
  __syncthreads();

  f32x16 acc0, acc1;  // rows 0..31 / 32..63 of this wave's (kh,sb) partial

  // ---------- stage A: T1 = xn0 @ layer0 (K=128, 4-way (p,kh) K-split) ----------
#pragma unroll
  for (int i = 0; i < 16; ++i) { acc0[i] = 0.f; acc1[i] = 0.f; }
  {
    const unsigned char* l0t = ws + WS_L0T;
#pragma unroll
    for (int kbL = 0; kbL < 2; ++kbL) {
      const int cb = (((p << 1) | kh) * 2 + kbL) * 32 + h * 16;
      f16x8 bf = *(const f16x8*)(l0t + scol * 256 + cb);
      f16x8 a0 = *(const f16x8*)(smem + SLOT0_OFF + l31 * 256 + (cb ^ swzA));
      f16x8 a1 = *(const f16x8*)(smem + SLOT0_OFF + (32 + l31) * 256 + (cb ^ swzA));
      acc0 = __builtin_amdgcn_mfma_f32_32x32x16_f16(a0, bf, acc0, 0, 0, 0);
      acc1 = __builtin_amdgcn_mfma_f32_32x32x16_f16(a1, bf, acc1, 0, 0, 0);
    }
  }
  reduce_T(smem, acc0, acc1, p, kh, h, scol);  // -> T1 (slots become scr)

  // ---------- stages B,C: T = KR(T, xn_l) @ core_l ----------
  for (int st = 0; st < 2; ++st) {
    const unsigned char* ctg = ws + (st ? WS_CT2 : WS_CT1);

    // prologue: chunk 0 -> slot 0 (scr data dead after reduce_T final sync)
    issue_chunk16(ctg, smem + SLOT0_OFF, tid);

    // T rows (both m-blocks x this wave's r-half K=32) into NAMED packed regs
    H2x4 tp00, tp01, tp10, tp11;   // tp<mb><kbL>
    {
      const int rb0 = kh * 64 + h * 16;
      tp00.v = *(const f16x8*)(smem + T_OFF + l31 * 128 + (rb0 ^ swzA));
      tp01.v = *(const f16x8*)(smem + T_OFF + l31 * 128 + ((rb0 + 32) ^ swzA));
      tp10.v = *(const f16x8*)(smem + T_OFF + (32 + l31) * 128 + (rb0 ^ swzA));
      tp11.v = *(const f16x8*)(smem + T_OFF + (32 + l31) * 128 + ((rb0 + 32) ^ swzA));
    }

#pragma unroll
    for (int i = 0; i < 16; ++i) { acc0[i] = 0.f; acc1[i] = 0.f; }

    // ring: chunk cg (2 d's) in slot (cg&1); 64 chunks cover d = 0..127
#pragma unroll 1
    for (int cg = 0; cg < 64; ++cg) {
      // xn reads for this wave's d = 2*cg + p, hoisted above the barrier
      // (XN12 is read-only during the loop -> safe before/after barrier).
      U1H2 e0, e1;
      {
        const unsigned char* xp = smem + XN12_OFF + (2 * cg + p) * 264 +
                                  4 * l31 + 2 * st;
        const unsigned xv0 = *(const unsigned short*)xp;
        const unsigned xv1 = *(const unsigned short*)(xp + 128);
        e0.u = xv0 | (xv0 << 16);
        e1.u = xv1 | (xv1 << 16);
      }
      WAITBAR0();   // chunk cg landed (issued >= 1 full iteration ago)
      if (cg < 63)
        issue_chunk16(ctg + (cg + 1) * 16384,
                      smem + ((cg + 1) & 1) * 16384, tid);
      // compute chunk cg: lane-contiguous fragment (read-once per wave)
      const unsigned char* bp = smem + (cg & 1) * 16384 +
                                p * 8192 + sb * 4096 + kh * 2048 + lp16;
      f16x8 bf0 = *(const f16x8*)(bp);
      f16x8 bf1 = *(const f16x8*)(bp + 1024);
      {  // kbL = 0
        H2x4 af0, af1;
#pragma unroll
        for (int q = 0; q < 4; ++q) {
          af0.h2[q] = __hmul2(tp00.h2[q], e0.h);
          af1.h2[q] = __hmul2(tp10.h2[q], e1.h);
        }
        acc0 = __builtin_amdgcn_mfma_f32_32x32x16_f16(af0.v, bf0, acc0, 0, 0, 0);
        acc1 = __builtin_amdgcn_mfma_f32_32x32x16_f16(af1.v, bf0, acc1, 0, 0, 0);
      }
      {  // kbL = 1
        H2x4 af0, af1;
#pragma unroll
        for (int q = 0; q < 4; ++q) {
          af0.h2[q] = __hmul2(tp01.h2[q], e0.h);
          af1.h2[q] = __hmul2(tp11.h2[q], e1.h);
        }
        acc0 = __builtin_amdgcn_mfma_f32_32x32x16_f16(af0.v, bf1, acc0, 0, 0, 0);
        acc1 = __builtin_amdgcn_mfma_f32_32x32x16_f16(af1.v, bf1, acc1, 0, 0, 0);
      }
    }
    reduce_T(smem, acc0, acc1, p, kh, h, scol);  // -> T2 then T3
  }

  // ---------- stage D: out = T3 @ last (p==0 waves; rows kh*32..) ----------
  if (p == 0) {
    f32x16 accd;
#pragma unroll
    for (int i = 0; i < 16; ++i) accd[i] = 0.f;
    const unsigned char* lastT = ws + WS_LASTT;
#pragma unroll
    for (int kb = 0; kb < 4; ++kb) {
      const int cb = kb * 32 + h * 16;
      f16x8 bf = *(const f16x8*)(lastT + scol * 128 + cb);
      f16x8 af = *(const f16x8*)(smem + T_OFF + (kh * 32 + l31) * 128 + (cb ^ swzA));
      accd = __builtin_amdgcn_mfma_f32_32x32x16_f16(af, bf, accd, 0, 0, 0);
    }
#pragma unroll
    for (int j = 0; j < 16; ++j) {
      const int r0 = (j & 3) + 8 * (j >> 2) + 4 * h;
      out[(size_t)(bg0 + kh * 32 + r0) * 64 + scol] = accd[j];
    }
  }
}

extern "C" void kernel_launch(void* const* d_in, const int* in_sizes, int n_in,
                              void* d_out, int out_size, void* d_ws, size_t ws_size,
                              hipStream_t stream) {
  const float* x      = (const float*)d_in[0];
  const float* layer0 = (const float*)d_in[1];
  const float* core1  = (const float*)d_in[2];
  const float* core2  = (const float*)d_in[3];
  const float* last   = (const float*)d_in[4];
  const float* lnw    = (const float*)d_in[5];
  const float* lnb    = (const float*)d_in[6];
  unsigned char* ws   = (unsigned char*)d_ws;
  float* outp         = (float*)d_out;

  tt_prep<<<1036, 512, 0, stream>>>(layer0, core1, core2, last, ws);
  tt_fused<<<512, 512, 0, stream>>>(x, lnw, lnb, ws, outp);
}

// Round 17
// 97.495 us; speedup vs baseline: 1.0997x; 1.0997x over previous
//
#include <hip/hip_runtime.h>
#include <hip/hip_fp16.h>

// B=32768, D=128, L=3, R=64, O=64. fp32 in/out, f16 MFMA compute.
// r14 schedule EXACTLY (TB=128, 16 waves p/kh/sb/mh, M-unroll 2, gathered
// ct layout, staged non-atomic reduce, T buffer, 32KB chunks, drain-0
// 2-slot ring, xn reads hoisted above the barrier). Codegen pass only:
// KR product as native f16x8 vector multiply (v_pk_mul_f16, no union
// marshalling), e as scalar _Float16 splat, loop-invariant addresses
// hoisted (bp slot-parity pair, xp running pointer, dh offsets as
// immediates). Same math, same schedule.
typedef _Float16 f16;
typedef _Float16 f16x8 __attribute__((ext_vector_type(8)));
typedef float f32x16 __attribute__((ext_vector_type(16)));

#define SPLAT8(s) ((f16x8){(s),(s),(s),(s),(s),(s),(s),(s)})

#define TB 128              // batch rows per workgroup (256 WGs = 1/CU)
// LDS layout (bytes)
#define SLOT0_OFF 0         // ring slot0 (32KB) = xn0 during phase0/stageA; scr0
#define SLOT1_OFF 32768     // ring slot1 (32KB); scr1
#define T_OFF     65536     // T buffer [128][64]f16, 128B rows, XOR swz = 16KB
#define XN12_OFF  81920     // xn slices 1,2: [d<128] pitch 520B = 66560B
#define SMEM_BYTES 148480   // 1 WG/CU (<= 163840)
// workspace layout (bytes)
#define WS_CT1   0          // core1 -> [d][sb][kh][kbL][lane][16B] f16, 1MB
#define WS_CT2   1048576    // core2 same
#define WS_L0T   2097152    // layer0^T [r][d] f16, 16KB
#define WS_LASTT 2113536    // last^T [o][r] f16, 8KB

#define WAITBAR0() asm volatile("s_waitcnt vmcnt(0)\n\ts_barrier" ::: "memory")

__device__ __forceinline__ void gload_lds16(const void* g, void* l) {
  __builtin_amdgcn_global_load_lds(
      (const __attribute__((address_space(1))) unsigned int*)g,
      (__attribute__((address_space(3))) unsigned int*)l, 16, 0, 0);
}

// stage one 32KB core chunk (4 d's): 2 loads/thread at 1024 threads
__device__ __forceinline__ void issue_chunk32(const unsigned char* g,
                                              unsigned char* l, int tid) {
  gload_lds16(g + tid * 16, l + tid * 16);
  gload_lds16(g + tid * 16 + 16384, l + tid * 16 + 16384);
}

__device__ __forceinline__ unsigned pack_h2(float a, float b) {
  return (unsigned)__half_as_ushort(__float2half(a)) |
         ((unsigned)__half_as_ushort(__float2half(b)) << 16);
}

// 4-way (p x kh) cross-wave reduce, staged non-atomic (r8 scheme):
// scr(kh) = 32KB f32 [128][64] in ring slot kh (both dead at reduce time),
// p0 writes, p1 adds, p0 combines kh-pair -> T [128][64] f16 swizzled.
__device__ __forceinline__ void reduce_T(unsigned char* smem, f32x16 a0, f32x16 a1,
                                         int p, int kh, int mh, int h, int scol) {
  float* scr = (float*)(smem + (kh ? SLOT1_OFF : SLOT0_OFF));
  __syncthreads();
  if (p == 0) {
#pragma unroll
    for (int j = 0; j < 16; ++j) {
      const int r0 = (j & 3) + 8 * (j >> 2) + 4 * h;
      const int row = mh * 64 + r0;
      scr[row * 64 + scol] = a0[j];
      scr[(row + 32) * 64 + scol] = a1[j];
    }
  }
  __syncthreads();
  if (p == 1) {
#pragma unroll
    for (int j = 0; j < 16; ++j) {
      const int r0 = (j & 3) + 8 * (j >> 2) + 4 * h;
      const int row = mh * 64 + r0;
      scr[row * 64 + scol] += a0[j];
      scr[(row + 32) * 64 + scol] += a1[j];
    }
  }
  __syncthreads();
  if (p == 0) {  // wave (kh,sb,mh) combines rows mh*64+kh*32.. across kh-pair
    const float* s0 = (const float*)(smem + SLOT0_OFF);
    const float* s1 = (const float*)(smem + SLOT1_OFF);
#pragma unroll
    for (int j = 0; j < 16; ++j) {
      const int r0 = (j & 3) + 8 * (j >> 2) + 4 * h;
      const int row = mh * 64 + kh * 32 + r0;
      const float vsum = s0[row * 64 + scol] + s1[row * 64 + scol];
      *(__half*)(smem + T_OFF + row * 128 + ((2 * scol) ^ ((row & 7) << 4))) =
          __float2half(vsum);
    }
  }
  __syncthreads();
}

// ---- prep: cast weights to f16 in the layouts the main kernel wants ----
__global__ void __launch_bounds__(512) tt_prep(
    const float* __restrict__ layer0, const float* __restrict__ core1,
    const float* __restrict__ core2, const float* __restrict__ last,
    unsigned char* __restrict__ ws) {
  const int tid = blockIdx.x * 512 + threadIdx.x;
  if (tid < 524288) {                       // ct: 2 x 262144 words
    const int which = tid >> 18;
    const int w = tid & 262143;
    const float* core = which ? core2 : core1;
    unsigned char* ct = ws + (which ? WS_CT2 : WS_CT1);
    // dest layout: [d][sb][kh][kbL][lp=l31*2+h][16B]; offset == w*4 (linear)
    const int j   = w & 3;                  // word within 16B chunk
    const int lp  = (w >> 2) & 63;          // l31*2 + h
    const int blk = w >> 8;                 // d*8 + sb*4 + kh*2 + kbL
    const int kbL = blk & 1;
    const int kh  = (blk >> 1) & 1;
    const int sb  = (blk >> 2) & 1;
    const int d   = blk >> 3;
    const int hh  = lp & 1;
    const int l31 = lp >> 1;
    const int s   = sb * 32 + l31;
    const int r0  = kh * 32 + kbL * 16 + hh * 8 + 2 * j;
    const unsigned val = pack_h2(core[r0 * 8192 + d * 64 + s],
                                 core[(r0 + 1) * 8192 + d * 64 + s]);
    *(unsigned*)(ct + (size_t)w * 4) = val;
  } else if (tid < 528384) {                // l0t: 4096 words, [r][d] f16 (256B rows)
    const int w = tid - 524288;
    const int r = w >> 6, j = w & 63, d = 2 * j;
    const unsigned val = pack_h2(layer0[d * 64 + r], layer0[(d + 1) * 64 + r]);
    *(unsigned*)(ws + WS_L0T + r * 256 + 4 * j) = val;
  } else if (tid < 530432) {                // lastT: 2048 words, [o][r] f16 (128B rows)
    const int w = tid - 528384;
    const int o = w >> 5, j = w & 31, r = 2 * j;
    const unsigned val = pack_h2(last[r * 64 + o], last[(r + 1) * 64 + o]);
    *(unsigned*)(ws + WS_LASTT + o * 128 + 4 * j) = val;
  }
}

// ---- fused main kernel: LN + 4-stage tensor-train chain ----
__global__ void __launch_bounds__(1024, 4) tt_fused(
    const float* __restrict__ x, const float* __restrict__ lnw,
    const float* __restrict__ lnb, const unsigned char* __restrict__ ws,
    float* __restrict__ out) {
  __shared__ alignas(16) unsigned char smem[SMEM_BYTES];
  const int tid = threadIdx.x;
  const int wid = tid >> 6;
  const int lane = tid & 63;
  const int l31 = lane & 31;
  const int h = lane >> 5;
  const int p  = wid & 1;           // d-parity within d-pair
  const int kh = (wid >> 1) & 1;    // r-half (K-split over r)
  const int sb = (wid >> 2) & 1;    // s-block (32 cols)
  const int mh = (wid >> 3) & 1;    // m-half (64 rows)
  const int bg0 = blockIdx.x * TB;
  const int scol = sb * 32 + l31;   // this lane's B-col
  const int lp16 = (l31 * 2 + h) * 16;
  const int swzA = (l31 & 7) << 4;  // == (row&7)<<4 for rows mb*32+l31

  // ---------- phase 0: LN; xn0 -> slot0 [row][256B swz]; xn1,2 -> XN12 ----------
  {
    float wv[6], bv[6];
#pragma unroll
    for (int k = 0; k < 6; ++k) { wv[k] = lnw[lane + 64 * k]; bv[k] = lnb[lane + 64 * k]; }
#pragma unroll
    for (int rr = 0; rr < 8; ++rr) {
      const int row = wid * 8 + rr;           // 16 waves x 8 = 128 rows
      const float* xrow = x + (size_t)(bg0 + row) * 384;
      float v[6];
#pragma unroll
      for (int k = 0; k < 6; ++k) v[k] = xrow[lane + 64 * k];
      float s = 0.f, ss = 0.f;
#pragma unroll
      for (int k = 0; k < 6; ++k) { s += v[k]; ss += v[k] * v[k]; }
#pragma unroll
      for (int m = 1; m < 64; m <<= 1) { s += __shfl_xor(s, m); ss += __shfl_xor(ss, m); }
      const float mu = s * (1.f / 384.f);
      const float var = ss * (1.f / 384.f) - mu * mu;
      const float rstd = rsqrtf(var + 1e-5f);
#pragma unroll
      for (int k = 0; k < 6; ++k) {
        const int i = lane + 64 * k;          // i = 3*d + sl
        const int d = i / 3;
        const int sl = i - 3 * d;
        const float xv = (v[k] - mu) * rstd * wv[k] + bv[k];
        if (sl == 0) {
          *(__half*)(smem + SLOT0_OFF + row * 256 + ((2 * d) ^ ((row & 7) << 4))) =
              __float2half(xv);
        } else {
          *(__half*)(smem + XN12_OFF + d * 520 + 4 * row + 2 * (sl - 1)) =
              __float2half(xv);
        }
      }
    }
  }
  __syncthreads();

  f32x16 acc0, acc1;  // rows mh*64+0..31 / mh*64+32..63 of (kh,sb) partial

  // ---------- stage A: T1 = xn0 @ layer0 (K=128, 4-way (p,kh) K-split) ----------
#pragma unroll
  for (int i = 0; i < 16; ++i) { acc0[i] = 0.f; acc1[i] = 0.f; }
  {
    const unsigned char* l0t = ws + WS_L0T;
#pragma unroll
    for (int kbL = 0; kbL < 2; ++kbL) {
      const int cb = (((p << 1) | kh) * 2 + kbL) * 32 + h * 16;
      f16x8 bf = *(const f16x8*)(l0t + scol * 256 + cb);
      f16x8 a0 = *(const f16x8*)(smem + SLOT0_OFF + (mh * 64 + l31) * 256 + (cb ^ swzA));
      f16x8 a1 = *(const f16x8*)(smem + SLOT0_OFF + (mh * 64 + 32 + l31) * 256 + (cb ^ swzA));
      acc0 = __builtin_amdgcn_mfma_f32_32x32x16_f16(a0, bf, acc0, 0, 0, 0);
      acc1 = __builtin_amdgcn_mfma_f32_32x32x16_f16(a1, bf, acc1, 0, 0, 0);
    }
  }
  reduce_T(smem, acc0, acc1, p, kh, mh, h, scol);  // -> T1 (slots become scr)

  // ---------- stages B,C: T = KR(T, xn_l) @ core_l ----------
  for (int st = 0; st < 2; ++st) {
    const unsigned char* ctg = ws + (st ? WS_CT2 : WS_CT1);

    // prologue: chunk 0 -> slot 0 (scr data dead after reduce_T final sync)
    issue_chunk32(ctg, smem + SLOT0_OFF, tid);

    // T rows (both m-blocks x this wave's r-half K=32) as plain f16x8 regs
    f16x8 tp00, tp01, tp10, tp11;   // tp<mb><kbL>
    {
      const int rb0 = kh * 64 + h * 16;
      const int ra = (mh * 64 + l31) * 128;
      const int rb = (mh * 64 + 32 + l31) * 128;
      tp00 = *(const f16x8*)(smem + T_OFF + ra + (rb0 ^ swzA));
      tp01 = *(const f16x8*)(smem + T_OFF + ra + ((rb0 + 32) ^ swzA));
      tp10 = *(const f16x8*)(smem + T_OFF + rb + (rb0 ^ swzA));
      tp11 = *(const f16x8*)(smem + T_OFF + rb + ((rb0 + 32) ^ swzA));
    }

#pragma unroll
    for (int i = 0; i < 16; ++i) { acc0[i] = 0.f; acc1[i] = 0.f; }

    // loop-invariant bases: bp per ring slot (dh offset folds into the
    // ds_read immediate), xp running pointer (stride 2080 = 4 d's x 520B)
    const unsigned char* bpS0 = smem + SLOT0_OFF + p * 8192 + sb * 4096 + kh * 2048 + lp16;
    const unsigned char* bpS1 = bpS0 + 32768;
    const unsigned char* xp = smem + XN12_OFF + p * 520 +
                              4 * (mh * 64 + l31) + 2 * st;

    // ring: chunk cg (4 d's) in slot (cg&1); issue cg+1 into the other slot
#pragma unroll 1
    for (int cg = 0; cg < 32; ++cg) {
      // xn scalars for both dh, hoisted above the barrier (XN12 read-only
      // during the loop -> safe). d = 4*cg + p (+2 for dh=1).
      const f16 ea0 = *(const f16*)(xp);           // dh0, mb0
      const f16 ea1 = *(const f16*)(xp + 128);     // dh0, mb1
      const f16 eb0 = *(const f16*)(xp + 1040);    // dh1, mb0
      const f16 eb1 = *(const f16*)(xp + 1168);    // dh1, mb1
      xp += 2080;
      WAITBAR0();   // chunk cg landed (issued >= 1 full iteration ago)
      if (cg < 31)
        issue_chunk32(ctg + (cg + 1) * 32768,
                      smem + ((cg + 1) & 1) * 32768, tid);
      const unsigned char* bp = (cg & 1) ? bpS1 : bpS0;
      // dh = 0 (dloc = p): fragment at bp, kbL pair at +0 / +1024
      {
        f16x8 bf0 = *(const f16x8*)(bp);
        f16x8 bf1 = *(const f16x8*)(bp + 1024);
        const f16x8 e0 = SPLAT8(ea0);
        const f16x8 e1 = SPLAT8(ea1);
        acc0 = __builtin_amdgcn_mfma_f32_32x32x16_f16(tp00 * e0, bf0, acc0, 0, 0, 0);
        acc1 = __builtin_amdgcn_mfma_f32_32x32x16_f16(tp10 * e1, bf0, acc1, 0, 0, 0);
        acc0 = __builtin_amdgcn_mfma_f32_32x32x16_f16(tp01 * e0, bf1, acc0, 0, 0, 0);
        acc1 = __builtin_amdgcn_mfma_f32_32x32x16_f16(tp11 * e1, bf1, acc1, 0, 0, 0);
      }
      // dh = 1 (dloc = p + 2): fragment at bp + 16384
      {
        f16x8 bf0 = *(const f16x8*)(bp + 16384);
        f16x8 bf1 = *(const f16x8*)(bp + 16384 + 1024);
        const f16x8 e0 = SPLAT8(eb0);
        const f16x8 e1 = SPLAT8(eb1);
        acc0 = __builtin_amdgcn_mfma_f32_32x32x16_f16(tp00 * e0, bf0, acc0, 0, 0, 0);
        acc1 = __builtin_amdgcn_mfma_f32_32x32x16_f16(tp10 * e1, bf0, acc1, 0, 0, 0);
        acc0 = __builtin_amdgcn_mfma_f32_32x32x16_f16(tp01 * e0, bf1, acc0, 0, 0, 0);
        acc1 = __builtin_amdgcn_mfma_f32_32x32x16_f16(tp11 * e1, bf1, acc1, 0, 0, 0);
      }
    }
    reduce_T(smem, acc0, acc1, p, kh, mh, h, scol);  // -> T2 then T3
  }

  // ---------- stage D: out = T3 @ last (p==0 waves; rows mh*64+kh*32..) ----------
  if (p == 0) {
    f32x16 accd;
#pragma unroll
    for (int i = 0; i < 16; ++i) accd[i] = 0.f;
    const unsigned char* lastT = ws + WS_LASTT;
    const int rbase = mh * 64 + kh * 32;
#pragma unroll
    for (int kb = 0; kb < 4; ++kb) {
      const int cb = kb * 32 + h * 16;
      f16x8 bf = *(const f16x8*)(lastT + scol * 128 + cb);
      f16x8 af = *(const f16x8*)(smem + T_OFF + (rbase + l31) * 128 + (cb ^ swzA));
      accd = __builtin_amdgcn_mfma_f32_32x32x16_f16(af, bf, accd, 0, 0, 0);
    }
#pragma unroll
    for (int j = 0; j < 16; ++j) {
      const int r0 = (j & 3) + 8 * (j >> 2) + 4 * h;
      out[(size_t)(bg0 + rbase + r0) * 64 + scol] = accd[j];
    }
  }
}

extern "C" void kernel_launch(void* const* d_in, const int* in_sizes, int n_in,
                              void* d_out, int out_size, void* d_ws, size_t ws_size,
                              hipStream_t stream) {
  const float* x      = (const float*)d_in[0];
  const float* layer0 = (const float*)d_in[1];
  const float* core1  = (const float*)d_in[2];
  const float* core2  = (const float*)d_in[3];
  const float* last   = (const float*)d_in[4];
  const float* lnw    = (const float*)d_in[5];
  const float* lnb    = (const float*)d_in[6];
  unsigned char* ws   = (unsigned char*)d_ws;
  float* outp         = (float*)d_out;

  tt_prep<<<1036, 512, 0, stream>>>(layer0, core1, core2, last, ws);
  tt_fused<<<256, 1024, 0, stream>>>(x, lnw, lnb, ws, outp);
}